// Round 2
// baseline (796.396 us; speedup 1.0000x reference)
//
#include <hip/hip_runtime.h>
#include <math.h>

// Problem: B=32, C=192, H=W=32, CH=8, stride=2 -> FEAT=2048, N=C*C=36864
// Pipeline: conv(+relu) -> linear -> per-batch LU (partial pivot) ->
//           weight = mats + P*(L*diag(d)) in-place -> out = weight @ inp ; logdet.

#define NFEAT 2048
#define NN    36864

// ---------------- Stage 1: conv partials (c-sliced) ----------------
// grid 128 = b*4+cs, block 256 (=16x16 output pixels). hpart[cs][b][ch*256+pix]
__global__ __launch_bounds__(256) void conv_kernel(const float* __restrict__ w,
                                                   const float* __restrict__ cw,
                                                   float* __restrict__ hpart) {
  int blk = blockIdx.x;
  int b = blk >> 2, cs = blk & 3;
  int tid = threadIdx.x;
  int oy = tid >> 4, ox = tid & 15;
  __shared__ float wlds[8 * 48 * 9];
  for (int idx = tid; idx < 8 * 48 * 9; idx += 256) {
    int ch = idx / 432, rem = idx - ch * 432;
    int c = rem / 9, kk = rem - c * 9;
    wlds[idx] = cw[ch * 1728 + (cs * 48 + c) * 9 + kk];
  }
  __syncthreads();
  float acc[8];
#pragma unroll
  for (int ch = 0; ch < 8; ++ch) acc[ch] = 0.f;
  const float* img0 = w + (((size_t)b * 192 + cs * 48) << 10);
  for (int c = 0; c < 48; ++c) {
    const float* img = img0 + ((size_t)c << 10);
    float iv[9];
#pragma unroll
    for (int ky = 0; ky < 3; ++ky)
#pragma unroll
      for (int kx = 0; kx < 3; ++kx) {
        int iy = 2 * oy - 1 + ky, ix = 2 * ox - 1 + kx;
        bool ok = (iy >= 0) & (iy < 32) & (ix >= 0) & (ix < 32);
        iv[ky * 3 + kx] = ok ? img[iy * 32 + ix] : 0.f;
      }
#pragma unroll
    for (int ch = 0; ch < 8; ++ch) {
      const float* wp = &wlds[(ch * 48 + c) * 9];
      float s = acc[ch];
#pragma unroll
      for (int t = 0; t < 9; ++t) s = fmaf(iv[t], wp[t], s);
      acc[ch] = s;
    }
  }
  size_t base = ((size_t)(cs * 32 + b) << 11) + tid;
#pragma unroll
  for (int ch = 0; ch < 8; ++ch) hpart[base + (ch << 8)] = acc[ch];
}

// ---------------- Stage 2: reduce partials + bias + relu -> h_t[k][b] ----------------
__global__ __launch_bounds__(256) void hreduce_kernel(const float* __restrict__ hpart,
                                                      const float* __restrict__ cb,
                                                      float* __restrict__ h_t) {
  int g = blockIdx.x * 256 + threadIdx.x;   // 0..65535
  int k = g & 2047, b = g >> 11;
  float s = 0.f;
#pragma unroll
  for (int cs = 0; cs < 4; ++cs) s += hpart[(((size_t)(cs * 32 + b)) << 11) + k];
  s += cb[k >> 8];
  s = fmaxf(s, 0.f);
  h_t[((size_t)k << 5) + b] = s;
}

// ---------------- Stage 3: linear  mats[b][n] = sum_k h[b][k]*lw[n][k] + lb[n] ------
// grid 576 (64 n per block); 4 waves split K into quarters of 512; lane <-> n.
__global__ __launch_bounds__(256) void linear_kernel(const float* __restrict__ h_t,
                                                     const float* __restrict__ lw,
                                                     const float* __restrict__ lb,
                                                     float* __restrict__ mats) {
  __shared__ float smem[4 * 64 * 68];   // W staging; aliased as accbuf[4][64][33]
  int tid = threadIdx.x;
  int l = tid & 63;
  int wq = __builtin_amdgcn_readfirstlane(tid >> 6);
  int n0 = blockIdx.x << 6;
  int kbase = wq << 9;
  float* wl = smem + wq * (64 * 68);
  float acc[32];
#pragma unroll
  for (int i = 0; i < 32; ++i) acc[i] = 0.f;
  for (int kc = 0; kc < 8; ++kc) {
    int koff = kbase + (kc << 6);
    // stage 64 rows x 64 k (coalesced float4), padded stride 68
#pragma unroll
    for (int j = 0; j < 16; ++j) {
      int f = l + (j << 6);
      int row = f >> 4, c4 = (f & 15) << 2;
      float4 v = *(const float4*)(lw + (size_t)(n0 + row) * 2048 + koff + c4);
      *(float4*)(wl + row * 68 + c4) = v;
    }
#pragma unroll 2
    for (int kk = 0; kk < 64; ++kk) {
      float wv = wl[l * 68 + kk];
      const float4* hp = (const float4*)(h_t + ((size_t)(koff + kk) << 5));
#pragma unroll
      for (int q = 0; q < 8; ++q) {
        float4 hv = hp[q];
        acc[4 * q + 0] = fmaf(hv.x, wv, acc[4 * q + 0]);
        acc[4 * q + 1] = fmaf(hv.y, wv, acc[4 * q + 1]);
        acc[4 * q + 2] = fmaf(hv.z, wv, acc[4 * q + 2]);
        acc[4 * q + 3] = fmaf(hv.w, wv, acc[4 * q + 3]);
      }
    }
  }
  __syncthreads();                       // all waves done with W staging regions
  float* accbuf = smem;                  // [4][64][33]
  float* mine = accbuf + (wq * 64 + l) * 33;
#pragma unroll
  for (int i = 0; i < 32; ++i) mine[i] = acc[i];
  __syncthreads();
#pragma unroll
  for (int r = 0; r < 8; ++r) {
    int q = r * 256 + tid;               // 0..2047
    int nsub = q & 63, b = q >> 6;
    float s = accbuf[(0 * 64 + nsub) * 33 + b] + accbuf[(1 * 64 + nsub) * 33 + b] +
              accbuf[(2 * 64 + nsub) * 33 + b] + accbuf[(3 * 64 + nsub) * 33 + b];
    s += lb[n0 + nsub];
    mats[(size_t)b * NN + n0 + nsub] = s;
  }
}

// ---------------- Stage 4: per-batch LU + in-place weight reconstruction ----------
// 32 blocks x 256 threads. Thread (g_r=tid&15, g_c=tid>>4) owns a[12][12]:
// rows g_r+16*rr, cols g_c+16*cc (interleaved). All register indices static.
__global__ __launch_bounds__(256, 1) void lu_kernel(float* __restrict__ A0,
                                                    const float* __restrict__ ssign,
                                                    float* __restrict__ ssum) {
  int b = blockIdx.x;
  float* __restrict__ A = A0 + (size_t)b * NN;
  int tid = threadIdx.x;
  int g_r = tid & 15, g_c = tid >> 4;
  __shared__ float bufK[192], bufP[192], mbuf[192], diagU[192], dval[192];
  __shared__ int perm[192];
  __shared__ int pivSh;
  for (int i = tid; i < 192; i += 256) perm[i] = i;
  float a[12][12];
#pragma unroll
  for (int rr = 0; rr < 12; ++rr)
#pragma unroll
    for (int cc = 0; cc < 12; ++cc)
      a[rr][cc] = A[(g_r + 16 * rr) * 192 + g_c + 16 * cc];
  __syncthreads();

  for (int k = 0; k < 192; ++k) {
    const int km = k & 15, kd = k >> 4;
    // phase 1: pivot candidates (col-k owners, one wave) + row-k -> bufK
    float bv = -1.f;
    int br = 0x7fffff;
    if (g_c == km) {
#pragma unroll
      for (int cc = 0; cc < 12; ++cc)
        if (cc == kd) {
#pragma unroll
          for (int rr = 0; rr < 12; ++rr) {
            int r = g_r + 16 * rr;
            float v = fabsf(a[rr][cc]);
            if (r >= k && v > bv) { bv = v; br = r; }   // ascending -> first max
          }
        }
    }
#pragma unroll
    for (int mask = 1; mask <= 8; mask <<= 1) {
      float ov = __shfl_xor(bv, mask, 64);
      int obr = __shfl_xor(br, mask, 64);
      if (ov > bv || (ov == bv && obr < br)) { bv = ov; br = obr; }
    }
    if (g_c == km && g_r == 0) pivSh = br;
    if (g_r == km) {
#pragma unroll
      for (int rr = 0; rr < 12; ++rr)
        if (rr == kd) {
#pragma unroll
          for (int cc = 0; cc < 12; ++cc) bufK[g_c + 16 * cc] = a[rr][cc];
        }
    }
    __syncthreads();  // bar1
    const int p = pivSh;
    const int pm = p & 15, pd = p >> 4;
    if (g_r == pm) {
#pragma unroll
      for (int rr = 0; rr < 12; ++rr)
        if (rr == pd) {
#pragma unroll
          for (int cc = 0; cc < 12; ++cc) bufP[g_c + 16 * cc] = a[rr][cc];
        }
    }
    __syncthreads();  // bar2
    if (tid == 0) {
      int t = perm[k]; perm[k] = perm[p]; perm[p] = t;
      diagU[k] = bufP[k];
    }
    if (p != k) {
      if (g_r == km) {
#pragma unroll
        for (int rr = 0; rr < 12; ++rr)
          if (rr == kd) {
#pragma unroll
            for (int cc = 0; cc < 12; ++cc) a[rr][cc] = bufP[g_c + 16 * cc];
          }
      }
      if (g_r == pm) {
#pragma unroll
        for (int rr = 0; rr < 12; ++rr)
          if (rr == pd) {
#pragma unroll
            for (int cc = 0; cc < 12; ++cc) a[rr][cc] = bufK[g_c + 16 * cc];
          }
      }
    }
    if (g_c == km) {                    // multipliers (LAPACK-style reciprocal)
      float rp = 1.0f / bufP[k];
#pragma unroll
      for (int cc = 0; cc < 12; ++cc)
        if (cc == kd) {
#pragma unroll
          for (int rr = 0; rr < 12; ++rr) {
            int r = g_r + 16 * rr;
            if (r > k) {
              float m = a[rr][cc] * rp;
              a[rr][cc] = m;
              mbuf[r] = m;
            } else
              mbuf[r] = 0.f;
          }
        }
    }
    __syncthreads();  // bar3
    // phase 4: rank-1 trailing update (zero-masked outside trailing block)
    float uv[12];
#pragma unroll
    for (int cc = 0; cc < 12; ++cc) {
      int c = g_c + 16 * cc;
      uv[cc] = (c > k) ? bufP[c] : 0.f;
    }
#pragma unroll
    for (int rr = 0; rr < 12; ++rr) {
      if (16 * rr + 15 > k) {
        float m = mbuf[g_r + 16 * rr];
#pragma unroll
        for (int cc = 0; cc < 12; ++cc) {
          if (16 * cc + 15 > k) a[rr][cc] = fmaf(-m, uv[cc], a[rr][cc]);
        }
      }
    }
  }
  // epilogue: logdet partial + weight = A + P*(L*diag(d)) in place
  if (tid == 0) {
    float s = 0.f;
    for (int i = 0; i < 192; ++i) s += diagU[i];
    ssum[b] = s;
  }
  for (int i = tid; i < 192; i += 256) dval[i] = ssign[i] * expf(diagU[i]) - diagU[i];
  __syncthreads();
#pragma unroll
  for (int rr = 0; rr < 12; ++rr) {
    int i = g_r + 16 * rr;
    int pi = perm[i];
    float di = dval[i];
    float* __restrict__ row = A + (size_t)pi * 192;
#pragma unroll
    for (int cc = 0; cc < 12; ++cc) {
      int j = g_c + 16 * cc;
      if (j < i)
        row[j] += a[rr][cc] * dval[j];
      else if (j == i)
        row[j] += di;
    }
  }
}

// ---------------- Stage 5: out[b] = weight[b] @ inp[b]  (+ logdet write) ----------
// grid 768 = b*24 + it*8 + jt ; tile 64(i) x 128(hw), BK=32, thread 8x4.
__global__ __launch_bounds__(256) void out_kernel(const float* __restrict__ wt,
                                                  const float* __restrict__ inp,
                                                  const float* __restrict__ ssum,
                                                  float* __restrict__ out) {
  int blk = blockIdx.x;
  int b = blk / 24, rem = blk % 24;
  int it = rem >> 3, jt = rem & 7;
  int i0 = it << 6, hw0 = jt << 7;
  int tid = threadIdx.x;
  int tx = tid & 31, ty = tid >> 5;
  __shared__ float wlds[64 * 36];
  __shared__ float xlds[32 * 128];
  const float* wb = wt + (size_t)b * NN;
  const float* xb = inp + (((size_t)b * 192) << 10);
  float acc[8][4];
#pragma unroll
  for (int r = 0; r < 8; ++r)
#pragma unroll
    for (int c = 0; c < 4; ++c) acc[r][c] = 0.f;
  for (int kc = 0; kc < 6; ++kc) {
    __syncthreads();
#pragma unroll
    for (int j = 0; j < 2; ++j) {
      int f4 = tid + (j << 8);
      int row = f4 >> 3, c4 = (f4 & 7) << 2;
      float4 v = *(const float4*)(wb + (size_t)(i0 + row) * 192 + (kc << 5) + c4);
      *(float4*)(wlds + row * 36 + c4) = v;
    }
#pragma unroll
    for (int j = 0; j < 4; ++j) {
      int f4 = tid + (j << 8);
      int row = f4 >> 5, c4 = (f4 & 31) << 2;
      float4 v = *(const float4*)(xb + (((size_t)(kc << 5) + row) << 10) + hw0 + c4);
      *(float4*)(xlds + (row << 7) + c4) = v;
    }
    __syncthreads();
#pragma unroll 4
    for (int k = 0; k < 32; ++k) {
      float4 xv = *(const float4*)(xlds + (k << 7) + (tx << 2));
      float wr[8];
#pragma unroll
      for (int r = 0; r < 8; ++r) wr[r] = wlds[(ty * 8 + r) * 36 + k];
#pragma unroll
      for (int r = 0; r < 8; ++r) {
        acc[r][0] = fmaf(wr[r], xv.x, acc[r][0]);
        acc[r][1] = fmaf(wr[r], xv.y, acc[r][1]);
        acc[r][2] = fmaf(wr[r], xv.z, acc[r][2]);
        acc[r][3] = fmaf(wr[r], xv.w, acc[r][3]);
      }
    }
  }
  float* ob = out + (((size_t)b * 192 + i0 + ty * 8) << 10) + hw0 + (tx << 2);
#pragma unroll
  for (int r = 0; r < 8; ++r) {
    float4 v = make_float4(acc[r][0], acc[r][1], acc[r][2], acc[r][3]);
    *(float4*)(ob + ((size_t)r << 10)) = v;
  }
  if (blk == 0 && tid == 0) {
    float s = 0.f;
    for (int i = 0; i < 32; ++i) s += ssum[i];
    out[6291456] = 32.f * s;   // H*W * mean over batch of sum(s)
  }
}

extern "C" void kernel_launch(void* const* d_in, const int* in_sizes, int n_in,
                              void* d_out, int out_size, void* d_ws, size_t ws_size,
                              hipStream_t stream) {
  const float* inp = (const float*)d_in[0];
  const float* wlo = (const float*)d_in[1];
  const float* cw  = (const float*)d_in[2];
  const float* cb  = (const float*)d_in[3];
  const float* lw  = (const float*)d_in[4];
  const float* lb  = (const float*)d_in[5];
  const float* ss  = (const float*)d_in[6];
  float* out = (float*)d_out;
  float* ws = (float*)d_ws;
  // ws layout (floats): hpart 262144 | h_t 65536 | mats 1179648 | ssum 32  (~6 MB)
  float* hpart = ws;
  float* h_t   = ws + 262144;
  float* mats  = ws + 327680;
  float* ssum  = ws + 1507328;
  hipLaunchKernelGGL(conv_kernel,    dim3(128), dim3(256), 0, stream, wlo, cw, hpart);
  hipLaunchKernelGGL(hreduce_kernel, dim3(256), dim3(256), 0, stream, hpart, cb, h_t);
  hipLaunchKernelGGL(linear_kernel,  dim3(576), dim3(256), 0, stream, h_t, lw, lb, mats);
  hipLaunchKernelGGL(lu_kernel,      dim3(32),  dim3(256), 0, stream, mats, ss, ssum);
  hipLaunchKernelGGL(out_kernel,     dim3(768), dim3(256), 0, stream, mats, inp, ssum, out);
}

// Round 3
// 734.952 us; speedup vs baseline: 1.0836x; 1.0836x over previous
//
#include <hip/hip_runtime.h>
#include <math.h>

// Problem: B=32, C=192, H=W=32, CH=8, stride=2 -> FEAT=2048, N=C*C=36864
// Pipeline: conv(+relu) -> linear -> per-batch LU (partial pivot) ->
//           weight = mats + P*(L*diag(d)) in-place -> out = weight @ inp ; logdet.

#define NFEAT 2048
#define NN    36864

// ---------------- Stage 1: conv partials (c-sliced) ----------------
// grid 128 = b*4+cs, block 256 (=16x16 output pixels). hpart[cs][b][ch*256+pix]
__global__ __launch_bounds__(256) void conv_kernel(const float* __restrict__ w,
                                                   const float* __restrict__ cw,
                                                   float* __restrict__ hpart) {
  int blk = blockIdx.x;
  int b = blk >> 2, cs = blk & 3;
  int tid = threadIdx.x;
  int oy = tid >> 4, ox = tid & 15;
  __shared__ float wlds[8 * 48 * 9];
  for (int idx = tid; idx < 8 * 48 * 9; idx += 256) {
    int ch = idx / 432, rem = idx - ch * 432;
    int c = rem / 9, kk = rem - c * 9;
    wlds[idx] = cw[ch * 1728 + (cs * 48 + c) * 9 + kk];
  }
  __syncthreads();
  float acc[8];
#pragma unroll
  for (int ch = 0; ch < 8; ++ch) acc[ch] = 0.f;
  const float* img0 = w + (((size_t)b * 192 + cs * 48) << 10);
  for (int c = 0; c < 48; ++c) {
    const float* img = img0 + ((size_t)c << 10);
    float iv[9];
#pragma unroll
    for (int ky = 0; ky < 3; ++ky)
#pragma unroll
      for (int kx = 0; kx < 3; ++kx) {
        int iy = 2 * oy - 1 + ky, ix = 2 * ox - 1 + kx;
        bool ok = (iy >= 0) & (iy < 32) & (ix >= 0) & (ix < 32);
        iv[ky * 3 + kx] = ok ? img[iy * 32 + ix] : 0.f;
      }
#pragma unroll
    for (int ch = 0; ch < 8; ++ch) {
      const float* wp = &wlds[(ch * 48 + c) * 9];
      float s = acc[ch];
#pragma unroll
      for (int t = 0; t < 9; ++t) s = fmaf(iv[t], wp[t], s);
      acc[ch] = s;
    }
  }
  size_t base = ((size_t)(cs * 32 + b) << 11) + tid;
#pragma unroll
  for (int ch = 0; ch < 8; ++ch) hpart[base + (ch << 8)] = acc[ch];
}

// ---------------- Stage 2: reduce partials + bias + relu -> h_t[k][b] ----------------
__global__ __launch_bounds__(256) void hreduce_kernel(const float* __restrict__ hpart,
                                                      const float* __restrict__ cb,
                                                      float* __restrict__ h_t) {
  int g = blockIdx.x * 256 + threadIdx.x;   // 0..65535
  int k = g & 2047, b = g >> 11;
  float s = 0.f;
#pragma unroll
  for (int cs = 0; cs < 4; ++cs) s += hpart[(((size_t)(cs * 32 + b)) << 11) + k];
  s += cb[k >> 8];
  s = fmaxf(s, 0.f);
  h_t[((size_t)k << 5) + b] = s;
}

// ---------------- Stage 3: linear  mats[b][n] = sum_k h[b][k]*lw[n][k] + lb[n] ------
// grid 576 (64 n per block); 4 waves split K into quarters of 512; lane <-> n.
__global__ __launch_bounds__(256) void linear_kernel(const float* __restrict__ h_t,
                                                     const float* __restrict__ lw,
                                                     const float* __restrict__ lb,
                                                     float* __restrict__ mats) {
  __shared__ float smem[4 * 64 * 68];   // W staging; aliased as accbuf[4][64][33]
  int tid = threadIdx.x;
  int l = tid & 63;
  int wq = __builtin_amdgcn_readfirstlane(tid >> 6);
  int n0 = blockIdx.x << 6;
  int kbase = wq << 9;
  float* wl = smem + wq * (64 * 68);
  float acc[32];
#pragma unroll
  for (int i = 0; i < 32; ++i) acc[i] = 0.f;
  for (int kc = 0; kc < 8; ++kc) {
    int koff = kbase + (kc << 6);
    // stage 64 rows x 64 k (coalesced float4), padded stride 68
#pragma unroll
    for (int j = 0; j < 16; ++j) {
      int f = l + (j << 6);
      int row = f >> 4, c4 = (f & 15) << 2;
      float4 v = *(const float4*)(lw + (size_t)(n0 + row) * 2048 + koff + c4);
      *(float4*)(wl + row * 68 + c4) = v;
    }
#pragma unroll 2
    for (int kk = 0; kk < 64; ++kk) {
      float wv = wl[l * 68 + kk];
      const float4* hp = (const float4*)(h_t + ((size_t)(koff + kk) << 5));
#pragma unroll
      for (int q = 0; q < 8; ++q) {
        float4 hv = hp[q];
        acc[4 * q + 0] = fmaf(hv.x, wv, acc[4 * q + 0]);
        acc[4 * q + 1] = fmaf(hv.y, wv, acc[4 * q + 1]);
        acc[4 * q + 2] = fmaf(hv.z, wv, acc[4 * q + 2]);
        acc[4 * q + 3] = fmaf(hv.w, wv, acc[4 * q + 3]);
      }
    }
  }
  __syncthreads();                       // all waves done with W staging regions
  float* accbuf = smem;                  // [4][64][33]
  float* mine = accbuf + (wq * 64 + l) * 33;
#pragma unroll
  for (int i = 0; i < 32; ++i) mine[i] = acc[i];
  __syncthreads();
#pragma unroll
  for (int r = 0; r < 8; ++r) {
    int q = r * 256 + tid;               // 0..2047
    int nsub = q & 63, b = q >> 6;
    float s = accbuf[(0 * 64 + nsub) * 33 + b] + accbuf[(1 * 64 + nsub) * 33 + b] +
              accbuf[(2 * 64 + nsub) * 33 + b] + accbuf[(3 * 64 + nsub) * 33 + b];
    s += lb[n0 + nsub];
    mats[(size_t)b * NN + n0 + nsub] = s;
  }
}

// ---------------- Stage 4: per-batch LU + in-place weight reconstruction ----------
// 32 blocks x 512 threads. Thread (g_r=tid&15, g_c=tid>>4 in 0..31) owns a[12][6]:
// rows g_r+16*rr, cols g_c+32*cc (interleaved). 72 floats/thread -> register-resident
// (R2 post-mortem: 144 floats/thread spilled to scratch, VGPR_Count=108, 512us).
// Same op order as R2 -> bit-identical arithmetic/pivots.
__global__ __launch_bounds__(512, 1) void lu_kernel(float* __restrict__ A0,
                                                    const float* __restrict__ ssign,
                                                    float* __restrict__ ssum) {
  int b = blockIdx.x;
  float* __restrict__ A = A0 + (size_t)b * NN;
  int tid = threadIdx.x;
  int g_r = tid & 15, g_c = tid >> 4;   // g_c in 0..31
  __shared__ float bufK[192], bufP[192], mbuf[192], diagU[192], dval[192];
  __shared__ int perm[192];
  __shared__ int pivSh;
  for (int i = tid; i < 192; i += 512) perm[i] = i;
  float a[12][6];
#pragma unroll
  for (int rr = 0; rr < 12; ++rr)
#pragma unroll
    for (int cc = 0; cc < 6; ++cc)
      a[rr][cc] = A[(g_r + 16 * rr) * 192 + g_c + 32 * cc];
  __syncthreads();

  for (int k = 0; k < 192; ++k) {
    const int km = k & 15, kd = k >> 4;     // row residue / row reg
    const int kcm = k & 31, kcd = k >> 5;   // col residue / col reg
    // phase 1: pivot candidates (col-k owners = 16 consecutive lanes of one wave)
    float bv = -1.f;
    int br = 0x7fffff;
    if (g_c == kcm) {
#pragma unroll
      for (int cc = 0; cc < 6; ++cc)
        if (cc == kcd) {
#pragma unroll
          for (int rr = 0; rr < 12; ++rr) {
            int r = g_r + 16 * rr;
            float v = fabsf(a[rr][cc]);
            if (r >= k && v > bv) { bv = v; br = r; }   // ascending -> first max
          }
        }
    }
#pragma unroll
    for (int mask = 1; mask <= 8; mask <<= 1) {
      float ov = __shfl_xor(bv, mask, 64);
      int obr = __shfl_xor(br, mask, 64);
      if (ov > bv || (ov == bv && obr < br)) { bv = ov; br = obr; }
    }
    if (g_c == kcm && g_r == 0) pivSh = br;
    // row-k extraction -> bufK (32 threads, one per col group)
    if (g_r == km) {
#pragma unroll
      for (int rr = 0; rr < 12; ++rr)
        if (rr == kd) {
#pragma unroll
          for (int cc = 0; cc < 6; ++cc) bufK[g_c + 32 * cc] = a[rr][cc];
        }
    }
    __syncthreads();  // bar1
    const int p = pivSh;
    const int pm = p & 15, pd = p >> 4;
    if (g_r == pm) {
#pragma unroll
      for (int rr = 0; rr < 12; ++rr)
        if (rr == pd) {
#pragma unroll
          for (int cc = 0; cc < 6; ++cc) bufP[g_c + 32 * cc] = a[rr][cc];
        }
    }
    __syncthreads();  // bar2
    if (tid == 0) {
      int t = perm[k]; perm[k] = perm[p]; perm[p] = t;
      diagU[k] = bufP[k];
    }
    if (p != k) {
      if (g_r == km) {
#pragma unroll
        for (int rr = 0; rr < 12; ++rr)
          if (rr == kd) {
#pragma unroll
            for (int cc = 0; cc < 6; ++cc) a[rr][cc] = bufP[g_c + 32 * cc];
          }
      }
      if (g_r == pm) {
#pragma unroll
        for (int rr = 0; rr < 12; ++rr)
          if (rr == pd) {
#pragma unroll
            for (int cc = 0; cc < 6; ++cc) a[rr][cc] = bufK[g_c + 32 * cc];
          }
      }
    }
    if (g_c == kcm) {                    // multipliers (LAPACK-style reciprocal)
      float rp = 1.0f / bufP[k];
#pragma unroll
      for (int cc = 0; cc < 6; ++cc)
        if (cc == kcd) {
#pragma unroll
          for (int rr = 0; rr < 12; ++rr) {
            int r = g_r + 16 * rr;
            if (r > k) {
              float m = a[rr][cc] * rp;
              a[rr][cc] = m;
              mbuf[r] = m;
            } else
              mbuf[r] = 0.f;
          }
        }
    }
    __syncthreads();  // bar3
    // phase 4: rank-1 trailing update (zero-masked outside trailing block)
    float uv[6];
#pragma unroll
    for (int cc = 0; cc < 6; ++cc) {
      int c = g_c + 32 * cc;
      uv[cc] = (c > k) ? bufP[c] : 0.f;
    }
#pragma unroll
    for (int rr = 0; rr < 12; ++rr) {
      if (16 * rr + 15 > k) {
        float m = mbuf[g_r + 16 * rr];
#pragma unroll
        for (int cc = 0; cc < 6; ++cc) {
          if (32 * cc + 31 > k) a[rr][cc] = fmaf(-m, uv[cc], a[rr][cc]);
        }
      }
    }
  }
  // epilogue: logdet partial + weight = A + P*(L*diag(d)) in place
  if (tid == 0) {
    float s = 0.f;
    for (int i = 0; i < 192; ++i) s += diagU[i];
    ssum[b] = s;
  }
  for (int i = tid; i < 192; i += 512) dval[i] = ssign[i] * expf(diagU[i]) - diagU[i];
  __syncthreads();
#pragma unroll
  for (int rr = 0; rr < 12; ++rr) {
    int i = g_r + 16 * rr;
    int pi = perm[i];
    float di = dval[i];
    float* __restrict__ row = A + (size_t)pi * 192;
#pragma unroll
    for (int cc = 0; cc < 6; ++cc) {
      int j = g_c + 32 * cc;
      if (j < i)
        row[j] += a[rr][cc] * dval[j];
      else if (j == i)
        row[j] += di;
    }
  }
}

// ---------------- Stage 5: out[b] = weight[b] @ inp[b]  (+ logdet write) ----------
// grid 768 = b*24 + it*8 + jt ; tile 64(i) x 128(hw), BK=32, thread 8x4.
__global__ __launch_bounds__(256) void out_kernel(const float* __restrict__ wt,
                                                  const float* __restrict__ inp,
                                                  const float* __restrict__ ssum,
                                                  float* __restrict__ out) {
  int blk = blockIdx.x;
  int b = blk / 24, rem = blk % 24;
  int it = rem >> 3, jt = rem & 7;
  int i0 = it << 6, hw0 = jt << 7;
  int tid = threadIdx.x;
  int tx = tid & 31, ty = tid >> 5;
  __shared__ float wlds[64 * 36];
  __shared__ float xlds[32 * 128];
  const float* wb = wt + (size_t)b * NN;
  const float* xb = inp + (((size_t)b * 192) << 10);
  float acc[8][4];
#pragma unroll
  for (int r = 0; r < 8; ++r)
#pragma unroll
    for (int c = 0; c < 4; ++c) acc[r][c] = 0.f;
  for (int kc = 0; kc < 6; ++kc) {
    __syncthreads();
#pragma unroll
    for (int j = 0; j < 2; ++j) {
      int f4 = tid + (j << 8);
      int row = f4 >> 3, c4 = (f4 & 7) << 2;
      float4 v = *(const float4*)(wb + (size_t)(i0 + row) * 192 + (kc << 5) + c4);
      *(float4*)(wlds + row * 36 + c4) = v;
    }
#pragma unroll
    for (int j = 0; j < 4; ++j) {
      int f4 = tid + (j << 8);
      int row = f4 >> 5, c4 = (f4 & 31) << 2;
      float4 v = *(const float4*)(xb + (((size_t)(kc << 5) + row) << 10) + hw0 + c4);
      *(float4*)(xlds + (row << 7) + c4) = v;
    }
    __syncthreads();
#pragma unroll 4
    for (int k = 0; k < 32; ++k) {
      float4 xv = *(const float4*)(xlds + (k << 7) + (tx << 2));
      float wr[8];
#pragma unroll
      for (int r = 0; r < 8; ++r) wr[r] = wlds[(ty * 8 + r) * 36 + k];
#pragma unroll
      for (int r = 0; r < 8; ++r) {
        acc[r][0] = fmaf(wr[r], xv.x, acc[r][0]);
        acc[r][1] = fmaf(wr[r], xv.y, acc[r][1]);
        acc[r][2] = fmaf(wr[r], xv.z, acc[r][2]);
        acc[r][3] = fmaf(wr[r], xv.w, acc[r][3]);
      }
    }
  }
  float* ob = out + (((size_t)b * 192 + i0 + ty * 8) << 10) + hw0 + (tx << 2);
#pragma unroll
  for (int r = 0; r < 8; ++r) {
    float4 v = make_float4(acc[r][0], acc[r][1], acc[r][2], acc[r][3]);
    *(float4*)(ob + ((size_t)r << 10)) = v;
  }
  if (blk == 0 && tid == 0) {
    float s = 0.f;
    for (int i = 0; i < 32; ++i) s += ssum[i];
    out[6291456] = 32.f * s;   // H*W * mean over batch of sum(s)
  }
}

extern "C" void kernel_launch(void* const* d_in, const int* in_sizes, int n_in,
                              void* d_out, int out_size, void* d_ws, size_t ws_size,
                              hipStream_t stream) {
  const float* inp = (const float*)d_in[0];
  const float* wlo = (const float*)d_in[1];
  const float* cw  = (const float*)d_in[2];
  const float* cb  = (const float*)d_in[3];
  const float* lw  = (const float*)d_in[4];
  const float* lb  = (const float*)d_in[5];
  const float* ss  = (const float*)d_in[6];
  float* out = (float*)d_out;
  float* ws = (float*)d_ws;
  // ws layout (floats): hpart 262144 | h_t 65536 | mats 1179648 | ssum 32  (~6 MB)
  float* hpart = ws;
  float* h_t   = ws + 262144;
  float* mats  = ws + 327680;
  float* ssum  = ws + 1507328;
  hipLaunchKernelGGL(conv_kernel,    dim3(128), dim3(256), 0, stream, wlo, cw, hpart);
  hipLaunchKernelGGL(hreduce_kernel, dim3(256), dim3(256), 0, stream, hpart, cb, h_t);
  hipLaunchKernelGGL(linear_kernel,  dim3(576), dim3(256), 0, stream, h_t, lw, lb, mats);
  hipLaunchKernelGGL(lu_kernel,      dim3(32),  dim3(512), 0, stream, mats, ss, ssum);
  hipLaunchKernelGGL(out_kernel,     dim3(768), dim3(256), 0, stream, mats, inp, ssum, out);
}